// Round 7
// baseline (304.763 us; speedup 1.0000x reference)
//
#include <hip/hip_runtime.h>
#include <stdint.h>

typedef __bf16 bf16x8 __attribute__((ext_vector_type(8)));
typedef float  f32x4  __attribute__((ext_vector_type(4)));

#define NB   32
#define CI   128
#define HH   56
#define WW   56
#define CO   256
#define HP   58          // 56 + 2 halo
#define HW   (HH*WW)     // 3136
#define MTOT (NB*HW)     // 100352
#define KTOT 1152        // 9*128, k = (r*3+s)*128 + c

#define XT_ELEMS ((size_t)NB*HP*HP*CI)   // 13,778,944
#define XT_BYTES (XT_ELEMS*2)            // 27,557,888 (16B-aligned)
#define WT_BYTES ((size_t)CO*KTOT*2)     // 589,824
#define CTR_OFF  (XT_BYTES + WT_BYTES)   // u32 tile counter in workspace

// ---------- fused prep: xpose (1792 blk) + wxform (1152 blk) + halo (456 blk) ----
#define XPOSE_BLOCKS (NB*HH)             // 1792
#define WX_BLOCKS    ((CO*KTOT)/256)     // 1152
#define HALO_BLOCKS  ((NB*228*16)/256)   // 456

__global__ void prep_kernel(const float* __restrict__ x, const float* __restrict__ wg,
                            __bf16* __restrict__ xt, __bf16* __restrict__ wt,
                            unsigned* __restrict__ ctr) {
  __shared__ float tile[CI][57];         // only used by xpose blocks
  int bx = blockIdx.x, t = threadIdx.x;
  if (bx == 0 && t == 0) *ctr = 0u;
  if (bx < XPOSE_BLOCKS) {
    int n = bx / HH, h = bx % HH;
    const float* src = x + (size_t)n * CI * HW + (size_t)h * WW;
    for (int idx = t; idx < CI * 14; idx += 256) {
      int c = idx / 14, w4 = idx - c * 14;
      float4 v = *(const float4*)(src + (size_t)c * HW + w4 * 4);
      tile[c][w4 * 4 + 0] = v.x;
      tile[c][w4 * 4 + 1] = v.y;
      tile[c][w4 * 4 + 2] = v.z;
      tile[c][w4 * 4 + 3] = v.w;
    }
    __syncthreads();
    __bf16* dst = xt + ((size_t)(n * HP + h + 1) * HP + 1) * CI;
    for (int idx = t; idx < WW * 16; idx += 256) {
      int w = idx >> 4, c8 = (idx & 15) * 8;
      bf16x8 v;
      for (int k = 0; k < 8; ++k) v[k] = (__bf16)tile[c8 + k][w];
      *(bf16x8*)(dst + (size_t)w * CI + c8) = v;
    }
  } else if (bx < XPOSE_BLOCKS + WX_BLOCKS) {
    int id = (bx - XPOSE_BLOCKS) * 256 + t;   // [0, CO*KTOT)
    int o = id / KTOT;
    int k = id - o * KTOT;
    int rs = k >> 7, c = k & 127;
    wt[id] = (__bf16)wg[(size_t)o * KTOT + c * 9 + rs];
  } else {
    int id = (bx - XPOSE_BLOCKS - WX_BLOCKS) * 256 + t;  // [0, NB*228*16)
    int chunk = id & 15;
    int p = (id >> 4) % 228;
    int n = id / (228 * 16);
    int h, w;
    if (p < 58)       { h = 0;           w = p; }
    else if (p < 116) { h = 57;          w = p - 58; }
    else if (p < 172) { h = p - 116 + 1; w = 0; }
    else              { h = p - 172 + 1; w = 57; }
    int4* dst = (int4*)(xt + ((size_t)(n * HP + h) * HP + w) * CI) + chunk;
    *dst = make_int4(0, 0, 0, 0);
  }
}

// ---------- implicit-GEMM conv: r1 3-buffer body + CONTINUOUS persistent pipeline ----
// r6 lesson: persistent with per-tile prologue serializes the boundary. Here the
// 3-buffer rotation (18 K-tiles % 3 == 0) carries across tiles: KBODY(16) of
// tile i stages tile i+1's T0' (next A-base, offs 0/0), KBODY(17) stages T1'
// (offs 128/128), both with steady vmcnt(6). Prologue runs ONCE per block.
// Boundary vmcnt audit (stores included): at each end-of-KBODY wait "6", the
// stage group needed next is always within the oldest (outstanding-6) ops:
//   KB17 end: out = T0'(6)+T1'(6) -> T0' done.   KB0' end: out = stores(16)+
//   T1'left+T2'(6) -> T1' (and all stores) done.  KB1' end: -> T2' done.  etc.
// Tail (no next tile): exact r1 drain path (DOSTAGE=0, vmcnt(0)).
// sh_nx handoff: written by t0 at loop-top, read after KB15's asm-"memory"
// (cannot hoist); >=16 barriers + lgkm drains in between for visibility.
#define BM 128
#define BN 256
#define NKT 18   // KTOT/64
#define NTILES (MTOT/BM)   // 784

__device__ __forceinline__ uint32_t offA_of(int kt) {
  int rs = kt >> 1; int r = (rs * 11) >> 5; int s = rs - 3 * r;
  return (uint32_t)((r * HP + s) * 256 + (kt & 1) * 128);
}

#define STAGE_A2(BS, OFF, AB) \
  { _Pragma("unroll") for (int i_ = 0; i_ < 2; ++i_) \
      __builtin_amdgcn_global_load_lds( \
        (const __attribute__((address_space(1))) void*)(xtc + (AB)[i_] + (OFF)), \
        (__attribute__((address_space(3))) void*)(lds + (BS)*16384 + i_*8192 + ldst), 16, 0, 0); }

#define STAGE_B01(BS, OFF) \
  { _Pragma("unroll") for (int i_ = 0; i_ < 2; ++i_) \
      __builtin_amdgcn_global_load_lds( \
        (const __attribute__((address_space(1))) void*)(wtc + baseB[i_] + (OFF)), \
        (__attribute__((address_space(3))) void*)(lds + 49152 + (BS)*32768 + i_*8192 + ldst), 16, 0, 0); }

#define STAGE_B23(BS, OFF) \
  { _Pragma("unroll") for (int i_ = 2; i_ < 4; ++i_) \
      __builtin_amdgcn_global_load_lds( \
        (const __attribute__((address_space(1))) void*)(wtc + baseB[i_] + (OFF)), \
        (__attribute__((address_space(3))) void*)(lds + 49152 + (BS)*32768 + i_*8192 + ldst), 16, 0, 0); }

// Compute from buf BC; optionally stage 6 issues (A-base AB, offsets OA/OB) into buf BS.
#define KBODY(BC, BS, DOSTAGE, DOBAR, VMCLIT, AB, OA, OB) do { \
  uint32_t offA2_ = (OA), offB2_ = (OB); \
  const char* Ab_ = lds + (BC)*16384; \
  const char* Bb_ = lds + 49152 + (BC)*32768; \
  bf16x8 av_[4][2], bva_[2][2], bvb_[2][2]; \
  _Pragma("unroll") for (int a_ = 0; a_ < 4; ++a_) { \
    av_[a_][0] = *(const bf16x8*)(Ab_ + rowA + a_*2048 + slot0); \
    av_[a_][1] = *(const bf16x8*)(Ab_ + rowA + a_*2048 + slot1); } \
  _Pragma("unroll") for (int b_ = 0; b_ < 2; ++b_) { \
    bva_[b_][0] = *(const bf16x8*)(Bb_ + rowB + b_*2048 + slot0); \
    bva_[b_][1] = *(const bf16x8*)(Bb_ + rowB + b_*2048 + slot1); } \
  if (DOSTAGE) { STAGE_A2(BS, offA2_, AB); STAGE_B01(BS, offB2_); } \
  __builtin_amdgcn_s_setprio(1); \
  _Pragma("unroll") for (int a_ = 0; a_ < 4; ++a_) { \
    _Pragma("unroll") for (int b_ = 0; b_ < 2; ++b_) { \
      acc[a_][b_] = __builtin_amdgcn_mfma_f32_16x16x32_bf16(av_[a_][0], bva_[b_][0], acc[a_][b_], 0, 0, 0); \
      acc[a_][b_] = __builtin_amdgcn_mfma_f32_16x16x32_bf16(av_[a_][1], bva_[b_][1], acc[a_][b_], 0, 0, 0); } } \
  __builtin_amdgcn_s_setprio(0); \
  _Pragma("unroll") for (int b_ = 0; b_ < 2; ++b_) { \
    bvb_[b_][0] = *(const bf16x8*)(Bb_ + rowB + 4096 + b_*2048 + slot0); \
    bvb_[b_][1] = *(const bf16x8*)(Bb_ + rowB + 4096 + b_*2048 + slot1); } \
  if (DOSTAGE) { STAGE_B23(BS, offB2_); } \
  __builtin_amdgcn_s_setprio(1); \
  _Pragma("unroll") for (int a_ = 0; a_ < 4; ++a_) { \
    _Pragma("unroll") for (int b_ = 0; b_ < 2; ++b_) { \
      acc[a_][b_+2] = __builtin_amdgcn_mfma_f32_16x16x32_bf16(av_[a_][0], bvb_[b_][0], acc[a_][b_+2], 0, 0, 0); \
      acc[a_][b_+2] = __builtin_amdgcn_mfma_f32_16x16x32_bf16(av_[a_][1], bvb_[b_][1], acc[a_][b_+2], 0, 0, 0); } } \
  __builtin_amdgcn_s_setprio(0); \
  if (DOBAR) { \
    asm volatile("s_waitcnt vmcnt(" VMCLIT ")" ::: "memory"); \
    __builtin_amdgcn_sched_barrier(0); \
    __builtin_amdgcn_s_barrier(); \
    __builtin_amdgcn_sched_barrier(0); } \
} while (0)

#define CALC_BASEA(DST, MB) \
  { _Pragma("unroll") for (int i_ = 0; i_ < 2; ++i_) { \
      unsigned m_ = (unsigned)(MB) * BM + i_ * 64 + arow; \
      unsigned nimg_ = m_ / HW; \
      unsigned hw_ = m_ - nimg_ * HW; \
      unsigned h_ = hw_ / WW; \
      unsigned w_ = hw_ - h_ * WW; \
      (DST)[i_] = ((nimg_ * HP + h_) * HP + w_) * (CI * 2) + kbsrc; } }

__global__ __launch_bounds__(512, 2) void conv_gemm(
    const __bf16* __restrict__ xt, const __bf16* __restrict__ wt,
    const float* __restrict__ bias, float* __restrict__ out,
    unsigned* __restrict__ ctr) {
  // LDS: A bufs 3x16384 @0 ; B bufs 3x32768 @49152 ; total 147456 B -> 1 blk/CU
  __shared__ char lds[147456];
  __shared__ int sh_mb, sh_nx;
  int t = threadIdx.x;
  const char* xtc = (const char*)xt;
  const char* wtc = (const char*)wt;

  // ---- staging geometry: linear LDS dest (t*16), PRE-SWIZZLED global source ----
  int arow = t >> 3;                                        // 0..63
  int kbsrc = ((t & 7) * 16) ^ ((arow & 7) << 4);           // swizzled slot in [0,128)
  int ldst = t * 16;
  uint32_t baseB[4];
#pragma unroll
  for (int i = 0; i < 4; ++i)
    baseB[i] = (i * 64 + arow) * (KTOT * 2) + kbsrc;

  // ---- per-wave geometry: 8 waves = 2M x 4N, each 64x64 quadrant ----
  int wid = t >> 6, lane = t & 63;
  int wm = (wid >> 2) * 64;        // 0,64
  int wn = (wid & 3) * 64;         // 0,64,128,192
  int lr = lane & 15, hi = lane >> 4;
  int swz = (lr & 7) << 4;
  int slot0 = (hi * 16) ^ swz;         // kk=0 slice, swizzled
  int slot1 = (64 + hi * 16) ^ swz;    // kk=1 slice
  int rowA = (wm + lr) * 128;          // + a*2048
  int rowB = (wn + lr) * 128;          // + b*2048

  // ---- first tile + one-time prologue ----
  if (t == 0) sh_mb = (int)atomicAdd(ctr, 1u);
  __syncthreads();
  int mb = sh_mb;
  if (mb >= NTILES) return;

  uint32_t baseA[2], baseN[2];
  CALC_BASEA(baseA, mb);

  STAGE_A2(0, 0u, baseA); STAGE_B01(0, 0u);   STAGE_B23(0, 0u);
  STAGE_A2(1, 128u, baseA); STAGE_B01(1, 128u); STAGE_B23(1, 128u);
  asm volatile("s_waitcnt vmcnt(6)" ::: "memory");
  __builtin_amdgcn_sched_barrier(0);
  __builtin_amdgcn_s_barrier();
  __builtin_amdgcn_sched_barrier(0);

  for (;;) {
    if (t == 0) sh_nx = (int)atomicAdd(ctr, 1u);   // read >=16 barriers later

    f32x4 acc[4][4];
#pragma unroll
    for (int i = 0; i < 4; ++i)
#pragma unroll
      for (int j = 0; j < 4; ++j) acc[i][j] = (f32x4){0.f, 0.f, 0.f, 0.f};

    // kt = 0..14 (5 x 3, buffers cycle 0,1,2), then kt=15: all steady.
#pragma unroll
    for (int kt = 0; kt < 15; kt += 3) {
      KBODY(0, 2, 1, 1, "6", baseA, offA_of(kt + 2), (uint32_t)((kt + 2) * 128));
      KBODY(1, 0, 1, 1, "6", baseA, offA_of(kt + 3), (uint32_t)((kt + 3) * 128));
      KBODY(2, 1, 1, 1, "6", baseA, offA_of(kt + 4), (uint32_t)((kt + 4) * 128));
    }
    KBODY(0, 2, 1, 1, "6", baseA, offA_of(17), (uint32_t)(17 * 128));  // kt=15

    int nx = sh_nx;                 // ordered after KB15's asm-"memory"
    bool have = nx < NTILES;
    CALC_BASEA(baseN, nx);          // not dereferenced unless have

    if (have) {
      // kt=16 computes buf1, stages next tile's T0' -> buf0 (offs 0/0)
      KBODY(1, 0, 1, 1, "6", baseN, 0u, 0u);
      // kt=17 computes buf2, stages next tile's T1' -> buf1 (offs 128/128)
      KBODY(2, 1, 1, 1, "6", baseN, 128u, 128u);
    } else {
      KBODY(1, 0, 0, 1, "0", baseA, 0u, 0u);
      KBODY(2, 1, 0, 0, "0", baseA, 0u, 0u);
    }

    // epilogue: C/D layout col(=o)=lane&15, row(=m)=(lane>>4)*4+reg
#pragma unroll
    for (int j = 0; j < 4; ++j) {
      int o = wn + j * 16 + lr;
      float bv = bias[o];
#pragma unroll
      for (int i = 0; i < 4; ++i) {
        unsigned m0 = (unsigned)mb * BM + wm + i * 16 + hi * 4;
        unsigned nimg = m0 / HW;
        unsigned hw = m0 - nimg * HW;
        f32x4 v = acc[i][j];
        v[0] += bv; v[1] += bv; v[2] += bv; v[3] += bv;
        *(f32x4*)(out + ((size_t)nimg * CO + o) * HW + hw) = v;
      }
    }

    if (!have) break;
    mb = nx;
    baseA[0] = baseN[0]; baseA[1] = baseN[1];
  }
}

extern "C" void kernel_launch(void* const* d_in, const int* in_sizes, int n_in,
                              void* d_out, int out_size, void* d_ws, size_t ws_size,
                              hipStream_t stream) {
  const float* x    = (const float*)d_in[0];
  const float* wg   = (const float*)d_in[1];
  const float* bias = (const float*)d_in[2];
  float* out = (float*)d_out;

  __bf16* xt = (__bf16*)d_ws;
  __bf16* wt = (__bf16*)((char*)d_ws + XT_BYTES);
  unsigned* ctr = (unsigned*)((char*)d_ws + CTR_OFF);

  prep_kernel<<<XPOSE_BLOCKS + WX_BLOCKS + HALO_BLOCKS, 256, 0, stream>>>(x, wg, xt, wt, ctr);
  conv_gemm<<<256, 512, 0, stream>>>(xt, wt, bias, out, ctr);
}

// Round 8
// 249.570 us; speedup vs baseline: 1.2212x; 1.2212x over previous
//
#include <hip/hip_runtime.h>
#include <stdint.h>

typedef __bf16 bf16x8 __attribute__((ext_vector_type(8)));
typedef float  f32x4  __attribute__((ext_vector_type(4)));

#define NB   32
#define CI   128
#define HH   56
#define WW   56
#define CO   256
#define HP   58          // 56 + 2 halo
#define HW   (HH*WW)     // 3136
#define MTOT (NB*HW)     // 100352
#define KTOT 1152        // 9*128, k = (r*3+s)*128 + c

#define XT_ELEMS ((size_t)NB*HP*HP*CI)   // 13,778,944
#define XT_BYTES (XT_ELEMS*2)            // 27,557,888 (16B-aligned)
#define WT_BYTES ((size_t)CO*KTOT*2)     // 589,824
#define CTR_OFF  (XT_BYTES + WT_BYTES)   // u32 tile counter in workspace

// ---------- fused prep: xpose (1792 blk) + wxform (1152 blk) + halo (456 blk) ----
#define XPOSE_BLOCKS (NB*HH)             // 1792
#define WX_BLOCKS    ((CO*KTOT)/256)     // 1152
#define HALO_BLOCKS  ((NB*228*16)/256)   // 456

__global__ void prep_kernel(const float* __restrict__ x, const float* __restrict__ wg,
                            __bf16* __restrict__ xt, __bf16* __restrict__ wt,
                            unsigned* __restrict__ ctr) {
  __shared__ float tile[CI][57];         // only used by xpose blocks
  int bx = blockIdx.x, t = threadIdx.x;
  if (bx == 0 && t == 0) *ctr = 0u;
  if (bx < XPOSE_BLOCKS) {
    int n = bx / HH, h = bx % HH;
    const float* src = x + (size_t)n * CI * HW + (size_t)h * WW;
    for (int idx = t; idx < CI * 14; idx += 256) {
      int c = idx / 14, w4 = idx - c * 14;
      float4 v = *(const float4*)(src + (size_t)c * HW + w4 * 4);
      tile[c][w4 * 4 + 0] = v.x;
      tile[c][w4 * 4 + 1] = v.y;
      tile[c][w4 * 4 + 2] = v.z;
      tile[c][w4 * 4 + 3] = v.w;
    }
    __syncthreads();
    __bf16* dst = xt + ((size_t)(n * HP + h + 1) * HP + 1) * CI;
    for (int idx = t; idx < WW * 16; idx += 256) {
      int w = idx >> 4, c8 = (idx & 15) * 8;
      bf16x8 v;
      for (int k = 0; k < 8; ++k) v[k] = (__bf16)tile[c8 + k][w];
      *(bf16x8*)(dst + (size_t)w * CI + c8) = v;
    }
  } else if (bx < XPOSE_BLOCKS + WX_BLOCKS) {
    int id = (bx - XPOSE_BLOCKS) * 256 + t;   // [0, CO*KTOT)
    int o = id / KTOT;
    int k = id - o * KTOT;
    int rs = k >> 7, c = k & 127;
    wt[id] = (__bf16)wg[(size_t)o * KTOT + c * 9 + rs];
  } else {
    int id = (bx - XPOSE_BLOCKS - WX_BLOCKS) * 256 + t;  // [0, NB*228*16)
    int chunk = id & 15;
    int p = (id >> 4) % 228;
    int n = id / (228 * 16);
    int h, w;
    if (p < 58)       { h = 0;           w = p; }
    else if (p < 116) { h = 57;          w = p - 58; }
    else if (p < 172) { h = p - 116 + 1; w = 0; }
    else              { h = p - 172 + 1; w = 57; }
    int4* dst = (int4*)(xt + ((size_t)(n * HP + h) * HP + w) * CI) + chunk;
    *dst = make_int4(0, 0, 0, 0);
  }
}

// ---------- implicit-GEMM conv: r1 3-buffer body + continuous persistent pipeline ----
// r7 post-mortem: the if/else boundary diamond (dup'd KBODYs + baseA/baseN both
// live) spilled acc (256 B/thr): WRITE +99 MB, FETCH +125 MB == 100 MB round trip.
// This version has ONE code path: KB16/KB17 ALWAYS stage (addresses = next tile
// if any, else current tile -> harmless re-stage once per block), and baseA is
// overwritten in place after its last use (KB15). Uniform vmcnt accounting:
//   end-KB15 "6" -> T16 done; end-KB16 (T17+T0'=12 out) -> T17 done;
//   end-KB17 -> T0' done; end-KB0' (T1'+stores+T2') -> T1' AND stores done.
// Never drains to 0. Tail: epilogue then return; s_endpgm drains leftovers.
#define BM 128
#define BN 256
#define NKT 18   // KTOT/64
#define NTILES (MTOT/BM)   // 784

__device__ __forceinline__ uint32_t offA_of(int kt) {
  int rs = kt >> 1; int r = (rs * 11) >> 5; int s = rs - 3 * r;
  return (uint32_t)((r * HP + s) * 256 + (kt & 1) * 128);
}

#define STAGE_A2(BS, OFF) \
  { _Pragma("unroll") for (int i_ = 0; i_ < 2; ++i_) \
      __builtin_amdgcn_global_load_lds( \
        (const __attribute__((address_space(1))) void*)(xtc + baseA[i_] + (OFF)), \
        (__attribute__((address_space(3))) void*)(lds + (BS)*16384 + i_*8192 + ldst), 16, 0, 0); }

#define STAGE_B01(BS, OFF) \
  { _Pragma("unroll") for (int i_ = 0; i_ < 2; ++i_) \
      __builtin_amdgcn_global_load_lds( \
        (const __attribute__((address_space(1))) void*)(wtc + baseB[i_] + (OFF)), \
        (__attribute__((address_space(3))) void*)(lds + 49152 + (BS)*32768 + i_*8192 + ldst), 16, 0, 0); }

#define STAGE_B23(BS, OFF) \
  { _Pragma("unroll") for (int i_ = 2; i_ < 4; ++i_) \
      __builtin_amdgcn_global_load_lds( \
        (const __attribute__((address_space(1))) void*)(wtc + baseB[i_] + (OFF)), \
        (__attribute__((address_space(3))) void*)(lds + 49152 + (BS)*32768 + i_*8192 + ldst), 16, 0, 0); }

// Compute from buf BC; stage 6 issues (offsets OA/OB) into buf BS.
#define KBODY(BC, BS, DOSTAGE, DOBAR, VMCLIT, OA, OB) do { \
  uint32_t offA2_ = (OA), offB2_ = (OB); \
  const char* Ab_ = lds + (BC)*16384; \
  const char* Bb_ = lds + 49152 + (BC)*32768; \
  bf16x8 av_[4][2], bva_[2][2], bvb_[2][2]; \
  _Pragma("unroll") for (int a_ = 0; a_ < 4; ++a_) { \
    av_[a_][0] = *(const bf16x8*)(Ab_ + rowA + a_*2048 + slot0); \
    av_[a_][1] = *(const bf16x8*)(Ab_ + rowA + a_*2048 + slot1); } \
  _Pragma("unroll") for (int b_ = 0; b_ < 2; ++b_) { \
    bva_[b_][0] = *(const bf16x8*)(Bb_ + rowB + b_*2048 + slot0); \
    bva_[b_][1] = *(const bf16x8*)(Bb_ + rowB + b_*2048 + slot1); } \
  if (DOSTAGE) { STAGE_A2(BS, offA2_); STAGE_B01(BS, offB2_); } \
  __builtin_amdgcn_s_setprio(1); \
  _Pragma("unroll") for (int a_ = 0; a_ < 4; ++a_) { \
    _Pragma("unroll") for (int b_ = 0; b_ < 2; ++b_) { \
      acc[a_][b_] = __builtin_amdgcn_mfma_f32_16x16x32_bf16(av_[a_][0], bva_[b_][0], acc[a_][b_], 0, 0, 0); \
      acc[a_][b_] = __builtin_amdgcn_mfma_f32_16x16x32_bf16(av_[a_][1], bva_[b_][1], acc[a_][b_], 0, 0, 0); } } \
  __builtin_amdgcn_s_setprio(0); \
  _Pragma("unroll") for (int b_ = 0; b_ < 2; ++b_) { \
    bvb_[b_][0] = *(const bf16x8*)(Bb_ + rowB + 4096 + b_*2048 + slot0); \
    bvb_[b_][1] = *(const bf16x8*)(Bb_ + rowB + 4096 + b_*2048 + slot1); } \
  if (DOSTAGE) { STAGE_B23(BS, offB2_); } \
  __builtin_amdgcn_s_setprio(1); \
  _Pragma("unroll") for (int a_ = 0; a_ < 4; ++a_) { \
    _Pragma("unroll") for (int b_ = 0; b_ < 2; ++b_) { \
      acc[a_][b_+2] = __builtin_amdgcn_mfma_f32_16x16x32_bf16(av_[a_][0], bvb_[b_][0], acc[a_][b_+2], 0, 0, 0); \
      acc[a_][b_+2] = __builtin_amdgcn_mfma_f32_16x16x32_bf16(av_[a_][1], bvb_[b_][1], acc[a_][b_+2], 0, 0, 0); } } \
  __builtin_amdgcn_s_setprio(0); \
  if (DOBAR) { \
    asm volatile("s_waitcnt vmcnt(" VMCLIT ")" ::: "memory"); \
    __builtin_amdgcn_sched_barrier(0); \
    __builtin_amdgcn_s_barrier(); \
    __builtin_amdgcn_sched_barrier(0); } \
} while (0)

#define CALC_BASEA(DST, MB) \
  { _Pragma("unroll") for (int i_ = 0; i_ < 2; ++i_) { \
      unsigned m_ = (unsigned)(MB) * BM + i_ * 64 + arow; \
      unsigned nimg_ = m_ / HW; \
      unsigned hw_ = m_ - nimg_ * HW; \
      unsigned h_ = hw_ / WW; \
      unsigned w_ = hw_ - h_ * WW; \
      (DST)[i_] = ((nimg_ * HP + h_) * HP + w_) * (CI * 2) + kbsrc; } }

__global__ __launch_bounds__(512, 2) void conv_gemm(
    const __bf16* __restrict__ xt, const __bf16* __restrict__ wt,
    const float* __restrict__ bias, float* __restrict__ out,
    unsigned* __restrict__ ctr) {
  // LDS: A bufs 3x16384 @0 ; B bufs 3x32768 @49152 ; total 147456 B -> 1 blk/CU
  __shared__ char lds[147456];
  __shared__ int sh_mb, sh_nx;
  int t = threadIdx.x;
  const char* xtc = (const char*)xt;
  const char* wtc = (const char*)wt;

  // ---- staging geometry: linear LDS dest (t*16), PRE-SWIZZLED global source ----
  int arow = t >> 3;                                        // 0..63
  int kbsrc = ((t & 7) * 16) ^ ((arow & 7) << 4);           // swizzled slot in [0,128)
  int ldst = t * 16;
  uint32_t baseB[4];
#pragma unroll
  for (int i = 0; i < 4; ++i)
    baseB[i] = (i * 64 + arow) * (KTOT * 2) + kbsrc;

  // ---- per-wave geometry: 8 waves = 2M x 4N, each 64x64 quadrant ----
  int wid = t >> 6, lane = t & 63;
  int wm = (wid >> 2) * 64;        // 0,64
  int wn = (wid & 3) * 64;         // 0,64,128,192
  int lr = lane & 15, hi = lane >> 4;
  int swz = (lr & 7) << 4;
  int slot0 = (hi * 16) ^ swz;         // kk=0 slice, swizzled
  int slot1 = (64 + hi * 16) ^ swz;    // kk=1 slice
  int rowA = (wm + lr) * 128;          // + a*2048
  int rowB = (wn + lr) * 128;          // + b*2048

  // ---- first tile + one-time prologue ----
  if (t == 0) sh_mb = (int)atomicAdd(ctr, 1u);
  __syncthreads();
  int mb = sh_mb;
  if (mb >= NTILES) return;

  uint32_t baseA[2];
  CALC_BASEA(baseA, mb);

  STAGE_A2(0, 0u);   STAGE_B01(0, 0u);   STAGE_B23(0, 0u);
  STAGE_A2(1, 128u); STAGE_B01(1, 128u); STAGE_B23(1, 128u);
  asm volatile("s_waitcnt vmcnt(6)" ::: "memory");
  __builtin_amdgcn_sched_barrier(0);
  __builtin_amdgcn_s_barrier();
  __builtin_amdgcn_sched_barrier(0);

  for (;;) {
    if (t == 0) sh_nx = (int)atomicAdd(ctr, 1u);   // read >=16 barriers later

    f32x4 acc[4][4];
#pragma unroll
    for (int i = 0; i < 4; ++i)
#pragma unroll
      for (int j = 0; j < 4; ++j) acc[i][j] = (f32x4){0.f, 0.f, 0.f, 0.f};

    // kt = 0..14 (5 x 3, buffers cycle 0,1,2), then kt=15: all steady.
#pragma unroll
    for (int kt = 0; kt < 15; kt += 3) {
      KBODY(0, 2, 1, 1, "6", offA_of(kt + 2), (uint32_t)((kt + 2) * 128));
      KBODY(1, 0, 1, 1, "6", offA_of(kt + 3), (uint32_t)((kt + 3) * 128));
      KBODY(2, 1, 1, 1, "6", offA_of(kt + 4), (uint32_t)((kt + 4) * 128));
    }
    KBODY(0, 2, 1, 1, "6", offA_of(17), (uint32_t)(17 * 128));  // kt=15

    // baseA dead from here; overwrite IN PLACE with next tile's base (or a
    // harmless self re-stage on the final tile) -- no diamond, no extra regs.
    int nx = sh_nx;                     // ordered after KB15's asm-"memory"
    int have = nx < NTILES;
    int nxm = have ? nx : mb;
    CALC_BASEA(baseA, nxm);

    // kt=16 computes buf1, stages T0' -> buf0; kt=17 computes buf2, stages T1' -> buf1.
    KBODY(1, 0, 1, 1, "6", 0u, 0u);
    KBODY(2, 1, 1, 1, "6", 128u, 128u);

    // epilogue: C/D layout col(=o)=lane&15, row(=m)=(lane>>4)*4+reg
#pragma unroll
    for (int j = 0; j < 4; ++j) {
      int o = wn + j * 16 + lr;
      float bv = bias[o];
#pragma unroll
      for (int i = 0; i < 4; ++i) {
        unsigned m0 = (unsigned)mb * BM + wm + i * 16 + hi * 4;
        unsigned nimg = m0 / HW;
        unsigned hw = m0 - nimg * HW;
        f32x4 v = acc[i][j];
        v[0] += bv; v[1] += bv; v[2] += bv; v[3] += bv;
        *(f32x4*)(out + ((size_t)nimg * CO + o) * HW + hw) = v;
      }
    }

    if (!have) return;                  // s_endpgm drains leftover stages
    mb = nx;
  }
}

extern "C" void kernel_launch(void* const* d_in, const int* in_sizes, int n_in,
                              void* d_out, int out_size, void* d_ws, size_t ws_size,
                              hipStream_t stream) {
  const float* x    = (const float*)d_in[0];
  const float* wg   = (const float*)d_in[1];
  const float* bias = (const float*)d_in[2];
  float* out = (float*)d_out;

  __bf16* xt = (__bf16*)d_ws;
  __bf16* wt = (__bf16*)((char*)d_ws + XT_BYTES);
  unsigned* ctr = (unsigned*)((char*)d_ws + CTR_OFF);

  prep_kernel<<<XPOSE_BLOCKS + WX_BLOCKS + HALO_BLOCKS, 256, 0, stream>>>(x, wg, xt, wt, ctr);
  conv_gemm<<<256, 512, 0, stream>>>(xt, wt, bias, out, ctr);
}